// Round 7
// baseline (255.288 us; speedup 1.0000x reference)
//
#include <hip/hip_runtime.h>
#include <stdint.h>

#define B_ 4
#define H_ 8
#define T_ 2048
#define C_ 1184
#define DK_ 148
#define DP_ 160
#define C3_ 3552

typedef __attribute__((ext_vector_type(8))) short s8v;
typedef __attribute__((ext_vector_type(4))) short s4v;
typedef __attribute__((ext_vector_type(4))) float f4v;
typedef __attribute__((ext_vector_type(16))) float f16v;

#define CSC 0.11858886f  /* log2(e)/sqrt(148) */

__device__ __forceinline__ unsigned short f2b(float f) {
  union { float f; unsigned u; } v; v.f = f;
  unsigned r = v.u + 0x7FFFu + ((v.u >> 16) & 1u);
  return (unsigned short)(r >> 16);
}

__device__ __forceinline__ void gld16(const void* g, void* l) {
  __builtin_amdgcn_global_load_lds(
      (const __attribute__((address_space(1))) void*)g,
      (__attribute__((address_space(3))) void*)l, 16, 0, 0);
}

#define SBAR() asm volatile("s_barrier" ::: "memory")
#define LGKM0()                                            \
  do {                                                     \
    asm volatile("s_waitcnt lgkmcnt(0)" ::: "memory");     \
    __builtin_amdgcn_sched_barrier(0);                     \
  } while (0)

__global__ __launch_bounds__(256) void cvt4(const float* __restrict__ src,
                                            short* __restrict__ dst, int n4) {
  int i = blockIdx.x * 256 + threadIdx.x;
  if (i >= n4) return;
  float4 f = ((const float4*)src)[i];
  s4v o = { (short)f2b(f.x), (short)f2b(f.y), (short)f2b(f.z), (short)f2b(f.w) };
  ((s4v*)dst)[i] = o;
}

// zero the d=148..159 pad of every Q/K row (contraction pads must be 0)
__global__ __launch_bounds__(256) void zpad(short* __restrict__ Qb,
                                            short* __restrict__ Kb) {
  const int row = blockIdx.x * 256 + threadIdx.x;  // 32*2048 rows
  const size_t off = (size_t)row * DP_ + DK_;
  const s4v z = { 0, 0, 0, 0 };
  *(s4v*)(Qb + off) = z; *(s4v*)(Qb + off + 4) = z; *(s4v*)(Qb + off + 8) = z;
  *(s4v*)(Kb + off) = z; *(s4v*)(Kb + off + 4) = z; *(s4v*)(Kb + off + 8) = z;
}

// ---------------------------------------------------------------------------
// QKV GEMM: C = A @ B^T + bias, scatter to Q/K/V^T.  256x256 tile, 8 waves
// (2M x 4N), BK=64, mfma 16x16x32 bf16.  m201-style schedule for K=1184:
// 18 full tiles (4 phases each) + 32-K tail.  LDS = 4 K-half slots x 16KB per
// operand (128KB): slot(t,kh) = (2t+kh)&3.  Each phase stages ONE half-tile
// 6 half-tiles ahead of its use; ONE s_waitcnt vmcnt(4) per tile (never 0
// until t=17) keeps 2 half-tiles in flight across every barrier.
// Granule swizzle: LDS granule g of row r holds source granule g ^ swz(r),
// swz(r) = (r ^ (r>>2)) & 3; read granule = hi ^ swz(lo).
// ---------------------------------------------------------------------------
template <int NT>
__global__ __launch_bounds__(512, 2) void gemm_qkv8(
    const short* __restrict__ A, const short* __restrict__ Bm,
    const float* __restrict__ bias,
    short* __restrict__ Qb, short* __restrict__ Kb, short* __restrict__ Vt) {
  __shared__ short As[4][8192];  // [slot][256 rows][4 granules][8 shorts]
  __shared__ short Bs[4][8192];
  const int tid = threadIdx.x;       // 0..511
  const int lane = tid & 63;
  const int wid = tid >> 6;          // 0..7
  const int lo = lane & 15, hi = lane >> 4;
  const int wr = wid >> 2, wc = wid & 3;  // 2 x 4 wave grid
  const int bid = blockIdx.x;
  const int xcd = bid & 7, kk = bid >> 3;
  const int m0 = (xcd * 4 + kk / NT) * 256;
  const int n0 = (kk % NT) * 256;

  // staging: thread covers rows rS and rS+128, LDS granule g = tid&3,
  // source granule g ^ swz(r)  (swz(r+128) == swz(r))
  const int rS = tid >> 2;
  const int gS = (tid & 3) ^ ((rS ^ (rS >> 2)) & 3);
  const short* pA0 = A + (size_t)(m0 + rS) * C_ + gS * 8;
  const short* pA1 = A + (size_t)(m0 + rS + 128) * C_ + gS * 8;
  const short* pB0 = Bm + (size_t)(n0 + rS) * C_ + gS * 8;
  const short* pB1 = Bm + (size_t)(n0 + rS + 128) * C_ + gS * 8;

#define STG_A(tt, khs, sl)                                      \
  do {                                                          \
    const int _o = (tt) * 64 + (khs) * 32;                      \
    gld16(pA0 + _o, &As[sl][tid * 8]);                          \
    gld16(pA1 + _o, &As[sl][(tid + 512) * 8]);                  \
  } while (0)
#define STG_B(tt, khs, sl)                                      \
  do {                                                          \
    const int _o = (tt) * 64 + (khs) * 32;                      \
    gld16(pB0 + _o, &Bs[sl][tid * 8]);                          \
    gld16(pB1 + _o, &Bs[sl][(tid + 512) * 8]);                  \
  } while (0)

  f4v acc[8][4] = {};
  const int gr = (hi ^ ((lo ^ (lo >> 2)) & 3)) * 8;  // read granule offset (shorts)
  const int rAb = wr * 128 + lo;                      // a-frag row base
  const int rBb = wc * 64 + lo;                       // b-frag row base

  // prologue: H0..H5 = {A,B}(t0,kh0) {A,B}(t0,kh1) {A,B}(t1,kh0)
  STG_A(0, 0, 0); STG_B(0, 0, 0);
  STG_A(0, 1, 1); STG_B(0, 1, 1);
  STG_A(1, 0, 2); STG_B(1, 0, 2);
  asm volatile("s_waitcnt vmcnt(4)" ::: "memory");  // t0 landed; t1-kh0 in flight
  SBAR();

#define MFMA16(base, bfr)                                                     \
  do {                                                                        \
    __builtin_amdgcn_s_setprio(1);                                            \
    _Pragma("unroll") for (int m = 0; m < 4; ++m)                             \
      _Pragma("unroll") for (int n = 0; n < 4; ++n)                           \
        acc[(base) + m][n] = __builtin_amdgcn_mfma_f32_16x16x32_bf16(         \
            af[m], bfr[n], acc[(base) + m][n], 0, 0, 0);                      \
    __builtin_amdgcn_s_setprio(0);                                            \
  } while (0)

  for (int t = 0; t < 18; ++t) {
    const int s0 = (2 * t) & 3;        // kh0 slot (also stage slot for t+2 kh0)
    const int s1 = s0 + 1;             // kh1 slot
    const int sN = (s0 + 3) & 3;       // stage slot for t+1 kh1
    const bool pf = (t < 17);
    s8v af[4], bf0[4], bf1[4];

    // ---- ph0: kh0 mq0; stage A(t+1,kh1) ----
#pragma unroll
    for (int n = 0; n < 4; ++n)
      bf0[n] = *(const s8v*)&Bs[s0][(rBb + n * 16) * 32 + gr];
#pragma unroll
    for (int m = 0; m < 4; ++m)
      af[m] = *(const s8v*)&As[s0][(rAb + m * 16) * 32 + gr];
    if (pf) STG_A(t + 1, 1, sN);
    SBAR(); LGKM0();
    MFMA16(0, bf0);
    SBAR();

    // ---- ph1: kh0 mq1; stage B(t+1,kh1) ----
#pragma unroll
    for (int m = 0; m < 4; ++m)
      af[m] = *(const s8v*)&As[s0][(rAb + 64 + m * 16) * 32 + gr];
    if (pf) STG_B(t + 1, 1, sN);
    SBAR(); LGKM0();
    MFMA16(4, bf0);
    SBAR();

    // ---- ph2: kh1 mq0; stage A(t+2,kh0) into just-freed s0 ----
#pragma unroll
    for (int n = 0; n < 4; ++n)
      bf1[n] = *(const s8v*)&Bs[s1][(rBb + n * 16) * 32 + gr];
#pragma unroll
    for (int m = 0; m < 4; ++m)
      af[m] = *(const s8v*)&As[s1][(rAb + m * 16) * 32 + gr];
    if (pf) STG_A(t + 2, 0, s0);
    SBAR(); LGKM0();
    MFMA16(0, bf1);
    SBAR();

    // ---- ph3: kh1 mq1; stage B(t+2,kh0); per-tile vmcnt gate ----
#pragma unroll
    for (int m = 0; m < 4; ++m)
      af[m] = *(const s8v*)&As[s1][(rAb + 64 + m * 16) * 32 + gr];
    if (pf) STG_B(t + 2, 0, s0);
    SBAR(); LGKM0();
    MFMA16(4, bf1);
    if (t < 17) asm volatile("s_waitcnt vmcnt(4)" ::: "memory");
    else        asm volatile("s_waitcnt vmcnt(0)" ::: "memory");
    SBAR();
  }

  // ---- tail tile (t=18, K=32, kh0 only, slot 0); all data landed ----
  {
    s8v af[4], bfT[4];
#pragma unroll
    for (int n = 0; n < 4; ++n)
      bfT[n] = *(const s8v*)&Bs[0][(rBb + n * 16) * 32 + gr];
#pragma unroll
    for (int m = 0; m < 4; ++m)
      af[m] = *(const s8v*)&As[0][(rAb + m * 16) * 32 + gr];
    MFMA16(0, bfT);
#pragma unroll
    for (int m = 0; m < 4; ++m)
      af[m] = *(const s8v*)&As[0][(rAb + 64 + m * 16) * 32 + gr];
    MFMA16(4, bfT);
  }
#undef MFMA16
#undef STG_A
#undef STG_B

  // epilogue: scatter to Q (scaled), K, V^T
#pragma unroll
  for (int n = 0; n < 4; ++n) {
    const int gn = n0 + wc * 64 + n * 16 + lo;
    if (gn < C3_) {
      const float bv = bias[gn];
      const int sel = gn / C_;
      const int r = gn - sel * C_;
      const int h = r / DK_;
      const int d = r - h * DK_;
#pragma unroll
      for (int m = 0; m < 8; ++m) {
        const int t0 = m0 + wr * 128 + (m >> 2) * 64 + (m & 3) * 16 + hi * 4;
        const int b = t0 >> 11, tt = t0 & 2047;
        const int bh = b * H_ + h;
        if (sel == 2) {  // V^T: 4 consecutive t for fixed d -> vector store
          s4v o = { (short)f2b(acc[m][n][0] + bv), (short)f2b(acc[m][n][1] + bv),
                    (short)f2b(acc[m][n][2] + bv), (short)f2b(acc[m][n][3] + bv) };
          *(s4v*)&Vt[((size_t)bh * DP_ + d) * T_ + tt] = o;
        } else {
#pragma unroll
          for (int j = 0; j < 4; ++j) {
            const short v = (sel == 0) ? (short)f2b((acc[m][n][j] + bv) * CSC)
                                       : (short)f2b(acc[m][n][j] + bv);
            if (sel == 0) Qb[((size_t)bh * T_ + tt + j) * DP_ + d] = v;
            else          Kb[((size_t)bh * T_ + tt + j) * DP_ + d] = v;
          }
        }
      }
    }
  }
}

// C = A @ B^T (+bias). 128x128 tile, 4 waves, mfma 16x16x32 bf16, BK=32,
// global_load_lds(16B) staging, double-buffered. XCD-chunked 1D grid.
// (out-projection)
template <int NT>
__global__ __launch_bounds__(256, 2) void gemm_bt(
    const short* __restrict__ A, const short* __restrict__ Bm,
    const float* __restrict__ bias, float* __restrict__ Out) {
  constexpr int K = C_;
  constexpr int NK = K / 32;  // 37
  __shared__ short As[2][128 * 32];
  __shared__ short Bs[2][128 * 32];
  const int tid = threadIdx.x;
  const int lane = tid & 63;
  const int wid = tid >> 6;
  const int lo = lane & 15, hi = lane >> 4;
  const int bid = blockIdx.x;
  const int xcd = bid & 7;
  const int kk = bid >> 3;
  const int m0 = (xcd * 8 + kk / NT) * 128;
  const int n0 = (kk % NT) * 128;
  const int wr = wid >> 1, wc = wid & 1;

  const int r0 = tid >> 2;
  const int sg = (tid & 3) * 8;
  const short* pa0 = A + (size_t)(m0 + r0) * K + sg;
  const short* pa1 = A + (size_t)(m0 + r0 + 64) * K + sg;
  const short* pb0 = Bm + (size_t)(n0 + r0) * K + sg;
  const short* pb1 = Bm + (size_t)(n0 + r0 + 64) * K + sg;

  f4v acc[4][4] = {};

#define STAGE(kk_, buf)                               \
  do {                                                \
    const int _o = (kk_) * 32;                        \
    gld16(pa0 + _o, &As[(buf)][tid * 8]);             \
    gld16(pa1 + _o, &As[(buf)][(tid + 256) * 8]);     \
    gld16(pb0 + _o, &Bs[(buf)][tid * 8]);             \
    gld16(pb1 + _o, &Bs[(buf)][(tid + 256) * 8]);     \
  } while (0)

  STAGE(0, 0);
  int cur = 0;
  for (int ks = 0; ks < NK; ++ks) {
    __syncthreads();  // drains vmcnt -> buf[cur] ready; buf[cur^1] consumed
    if (ks + 1 < NK) STAGE(ks + 1, cur ^ 1);
    const short* Ab = As[cur];
    const short* Bb = Bs[cur];
    s8v af[4], bf[4];
#pragma unroll
    for (int m = 0; m < 4; ++m)
      af[m] = *(const s8v*)&Ab[(wr * 64 + m * 16 + lo) * 32 + hi * 8];
#pragma unroll
    for (int n = 0; n < 4; ++n)
      bf[n] = *(const s8v*)&Bb[(wc * 64 + n * 16 + lo) * 32 + hi * 8];
#pragma unroll
    for (int m = 0; m < 4; ++m)
#pragma unroll
      for (int n = 0; n < 4; ++n)
        acc[m][n] = __builtin_amdgcn_mfma_f32_16x16x32_bf16(af[m], bf[n], acc[m][n], 0, 0, 0);
    cur ^= 1;
  }
#undef STAGE

#pragma unroll
  for (int n = 0; n < 4; ++n) {
    const int gn = n0 + wc * 64 + n * 16 + lo;
    if (gn < C_) {
      const float bv = bias[gn];
#pragma unroll
      for (int m = 0; m < 4; ++m)
#pragma unroll
        for (int j = 0; j < 4; ++j) {
          const int gm = m0 + wr * 64 + m * 16 + hi * 4 + j;
          Out[(size_t)gm * C_ + gn] = acc[m][n][j] + bv;
        }
    }
  }
}

// Causal flash attention, 32x32x16 MFMA path, no P LDS round-trip.
// (unchanged from round 5)
__global__ __launch_bounds__(256, 2) void attn(
    const short* __restrict__ Qb, const short* __restrict__ Kb,
    const short* __restrict__ Vt, short* __restrict__ Y) {
  __shared__ short Ks[2][10240];  // [5 c][64 r][4 w] granules(8sh), w ^= (r>>1)&3
  __shared__ short Vs[2][10240];  // [160 d][8 v] granules, v ^= d&7
  const int tid = threadIdx.x;
  const int lane = tid & 63;
  const int wid = tid >> 6;
  const int q31 = lane & 31;
  const int h32 = lane >> 5;
  const int s = blockIdx.x;
  const int xcd = s & 7;
  const int k = s >> 3;
  int qb, bsub;
  if (k < 32) { bsub = k >> 4; qb = k & 15; }
  else { bsub = 2 + ((k - 32) >> 4); qb = 15 - (k & 15); }
  const int bh = xcd * 4 + bsub;
  const int q0 = qb * 128 + wid * 32;
  const short* Qh = Qb + (size_t)bh * T_ * DP_;
  const short* Kh = Kb + (size_t)bh * T_ * DP_;
  const short* Vh = Vt + (size_t)bh * DP_ * T_;

  s8v qf[10];
#pragma unroll
  for (int c = 0; c < 10; ++c)
    qf[c] = *(const s8v*)(Qh + (size_t)(q0 + q31) * DP_ + c * 16 + h32 * 8);

  f16v acc[5] = {};
  float mrun = -INFINITY, lrun = 0.f;
  const int nt = 2 * (qb + 1);

#define STAGEKV(kt_, buf_)                                                   \
  do {                                                                       \
    const size_t kvo_ = (size_t)(kt_) * 64;                                  \
    _Pragma("unroll")                                                        \
    for (int i_ = 0; i_ < 5; ++i_) {                                         \
      const int g_ = tid + i_ * 256;                                         \
      const int c_ = g_ >> 8, re_ = g_ & 255, r_ = re_ >> 2, wz_ = re_ & 3;  \
      const int w_ = wz_ ^ ((r_ >> 1) & 3);                                  \
      gld16(Kh + (kvo_ + r_) * DP_ + c_ * 32 + w_ * 8, &Ks[buf_][g_ * 8]);   \
      const int d_ = g_ >> 3, vz_ = g_ & 7;                                  \
      const int v_ = vz_ ^ (d_ & 7);                                         \
      gld16(Vh + (size_t)d_ * T_ + kvo_ + v_ * 8, &Vs[buf_][g_ * 8]);        \
    }                                                                        \
  } while (0)

  STAGEKV(0, 0);
  int cur = 0;
  for (int kt = 0; kt < nt; ++kt) {
    __syncthreads();
    if (kt + 1 < nt) STAGEKV(kt + 1, cur ^ 1);
    const int kv0 = kt * 64;
    if (kv0 <= q0 + 31) {
      const short* Kc = Ks[cur];
      const short* Vc = Vs[cur];
      f16v sc[2] = {};
      __builtin_amdgcn_s_setprio(1);
#pragma unroll
      for (int t2 = 0; t2 < 2; ++t2) {
        const int r_ = t2 * 32 + q31;
#pragma unroll
        for (int c16 = 0; c16 < 10; ++c16) {
          const int u_ = 2 * c16 + h32;
          const int w_ = (u_ & 3) ^ ((r_ >> 1) & 3);
          s8v kf = *(const s8v*)&Kc[((u_ >> 2) * 256 + r_ * 4 + w_) * 8];
          sc[t2] = __builtin_amdgcn_mfma_f32_32x32x16_bf16(kf, qf[c16], sc[t2], 0, 0, 0);
        }
      }
      __builtin_amdgcn_s_setprio(0);
      const int qrow = q0 + q31;
      if (kv0 + 63 > q0) {
#pragma unroll
        for (int t2 = 0; t2 < 2; ++t2)
#pragma unroll
          for (int g = 0; g < 4; ++g)
#pragma unroll
            for (int j = 0; j < 4; ++j)
              if (kv0 + t2 * 32 + 8 * g + 4 * h32 + j > qrow)
                sc[t2][4 * g + j] = -INFINITY;
      }
      float tm = -INFINITY;
#pragma unroll
      for (int t2 = 0; t2 < 2; ++t2)
#pragma unroll
        for (int r = 0; r < 16; ++r) tm = fmaxf(tm, sc[t2][r]);
      tm = fmaxf(tm, __shfl_xor(tm, 32));
      if (!__all(tm <= mrun + 8.f)) {
        const float nm = fmaxf(mrun, tm);
        const float corr = exp2f(mrun - nm);
        mrun = nm;
        lrun *= corr;
#pragma unroll
        for (int dt = 0; dt < 5; ++dt)
#pragma unroll
          for (int r = 0; r < 16; ++r) acc[dt][r] *= corr;
      }
      float ps = 0.f;
#pragma unroll
      for (int t2 = 0; t2 < 2; ++t2)
#pragma unroll
        for (int r = 0; r < 16; ++r) {
          sc[t2][r] = exp2f(sc[t2][r] - mrun);
          ps += sc[t2][r];
        }
      ps += __shfl_xor(ps, 32);
      lrun += ps;
#pragma unroll
      for (int st = 0; st < 4; ++st) {
        const int t2 = st >> 1, g4 = (st & 1) * 8;
        unsigned wA0 = (unsigned)f2b(sc[t2][g4 + 0]) | ((unsigned)f2b(sc[t2][g4 + 1]) << 16);
        unsigned wA1 = (unsigned)f2b(sc[t2][g4 + 2]) | ((unsigned)f2b(sc[t2][g4 + 3]) << 16);
        unsigned wB0 = (unsigned)f2b(sc[t2][g4 + 4]) | ((unsigned)f2b(sc[t2][g4 + 5]) << 16);
        unsigned wB1 = (unsigned)f2b(sc[t2][g4 + 6]) | ((unsigned)f2b(sc[t2][g4 + 7]) << 16);
        const unsigned sxA0 = (unsigned)__shfl_xor((int)wA0, 32);
        const unsigned sxA1 = (unsigned)__shfl_xor((int)wA1, 32);
        const unsigned sxB0 = (unsigned)__shfl_xor((int)wB0, 32);
        const unsigned sxB1 = (unsigned)__shfl_xor((int)wB1, 32);
        union { unsigned w[4]; s8v v; } pf;
        pf.w[0] = h32 ? sxB0 : wA0;
        pf.w[1] = h32 ? sxB1 : wA1;
        pf.w[2] = h32 ? wB0 : sxA0;
        pf.w[3] = h32 ? wB1 : sxA1;
        __builtin_amdgcn_s_setprio(1);
#pragma unroll
        for (int dt = 0; dt < 5; ++dt) {
          const int d_ = dt * 32 + q31;
          const int sl_ = (st * 2 + h32) ^ (d_ & 7);
          s8v vf = *(const s8v*)&Vc[(d_ * 8 + sl_) * 8];
          acc[dt] = __builtin_amdgcn_mfma_f32_32x32x16_bf16(vf, pf.v, acc[dt], 0, 0, 0);
        }
        __builtin_amdgcn_s_setprio(0);
      }
    }
    cur ^= 1;
  }
#undef STAGEKV

  const float inv = 1.0f / lrun;
  const int b = bh >> 3, h = bh & 7;
  const int trow = q0 + q31;
  const size_t ybase = ((size_t)(b * T_ + trow)) * C_ + h * DK_;
#pragma unroll
  for (int dt = 0; dt < 5; ++dt)
#pragma unroll
    for (int g = 0; g < 4; ++g) {
      const int d0 = dt * 32 + 8 * g + 4 * h32;
      if (d0 + 3 < DK_) {
        s4v o = { (short)f2b(acc[dt][4 * g + 0] * inv), (short)f2b(acc[dt][4 * g + 1] * inv),
                  (short)f2b(acc[dt][4 * g + 2] * inv), (short)f2b(acc[dt][4 * g + 3] * inv) };
        *(s4v*)(Y + ybase + d0) = o;
      }
    }
}

extern "C" void kernel_launch(void* const* d_in, const int* in_sizes, int n_in,
                              void* d_out, int out_size, void* d_ws, size_t ws_size,
                              hipStream_t stream) {
  const float* x  = (const float*)d_in[0];
  const float* wA = (const float*)d_in[1];
  const float* bA = (const float*)d_in[2];
  const float* wP = (const float*)d_in[3];
  const float* bP = (const float*)d_in[4];
  float* out = (float*)d_out;

  short* ws  = (short*)d_ws;
  short* xb  = ws;                  // [8192][1184] bf16; later reused as Y
  short* wab = xb + 9699328;        // [3584][1184]
  short* wpb = wab + 4243456;       // [1280][1184]
  short* Qb  = wpb + 1515520;       // [32][2048][160]
  short* Kb  = Qb + 10485760;       // [32][2048][160]
  short* Vt  = Kb + 10485760;       // [32][160][2048]

  cvt4<<<(9699328 / 4 + 255) / 256, 256, 0, stream>>>(x, xb, 9699328 / 4);
  cvt4<<<(4205568 / 4 + 255) / 256, 256, 0, stream>>>(wA, wab, 4205568 / 4);
  cvt4<<<(1401856 / 4 + 255) / 256, 256, 0, stream>>>(wP, wpb, 1401856 / 4);
  zpad<<<256, 256, 0, stream>>>(Qb, Kb);  // zero d=148..159 contraction pads

  // qkv: 32 m-tiles x 14 n-tiles, XCD-chunked (448 % 8 == 0)
  gemm_qkv8<14><<<448, 512, 0, stream>>>(xb, wab, bA, Qb, Kb, Vt);
  attn<<<512, 256, 0, stream>>>(Qb, Kb, Vt, xb);  // Y aliases xb (dead)
  gemm_bt<10><<<640, 256, 0, stream>>>(xb, wpb, bP, out);
}